// Round 9
// baseline (596.101 us; speedup 1.0000x reference)
//
#include <hip/hip_runtime.h>

#define SEQ   4096
#define HH    4
#define SCALE 0.125f

typedef __bf16 bf16x8 __attribute__((ext_vector_type(8)));
typedef float  f32x4  __attribute__((ext_vector_type(4)));

// ---- ws layout (float offsets), 56.9 MB total (< proven 70.5 MB) ----
// Facts: inputs fp32, output fp32 (R6 probe), ws >= 70.5 MB (R2==R3).
constexpr size_t OFF_WQT = 0;        // transposed weights, 65536 each
constexpr size_t OFF_WKT = 65536;
constexpr size_t OFF_WVT = 131072;
constexpr size_t OFF_WOT = 196608;
constexpr size_t OFF_A   = 262144;   // [bh*S+j] a_j = -16 - ln(Z_j)
constexpr size_t OFF_PZ  = 458752;   // [4][32768] partial shifted sums
constexpr size_t OFF_Q16 = 2686976;  // bf16 region (float offset)
constexpr size_t K16OFF  = 2097152;  // bf16-elem offsets within region
constexpr size_t V16OFF  = 4194304;  // V stored TRANSPOSED [bh][d][s]
constexpr size_t OFF_PO  = 5832704;  // [4jy][8bh][4096 i][64 d] fp32 partial O

__device__ __forceinline__ f32x4 mf(bf16x8 a, bf16x8 b, f32x4 c) {
    return __builtin_amdgcn_mfma_f32_16x16x32_bf16(a, b, c, 0, 0, 0);
}

// ---- LDS-tiled weight transpose to [k][n] fp32 ----
__global__ void k_transpose(const float* __restrict__ wq, const float* __restrict__ wk,
                            const float* __restrict__ wv, const float* __restrict__ wo,
                            float* __restrict__ ws) {
    __shared__ float tile[64][65];
    int y = blockIdx.z;
    const float* src = (y == 0) ? wq : (y == 1) ? wk : (y == 2) ? wv : wo;
    int k0 = blockIdx.x * 64, t0 = blockIdx.y * 64;
    int c = threadIdx.x & 63, r4 = threadIdx.x >> 6;
    for (int rr = r4; rr < 64; rr += 4)
        tile[rr][c] = src[(size_t)(t0 + rr) * 256 + k0 + c];
    __syncthreads();
    for (int rr = r4; rr < 64; rr += 4)
        ws[(size_t)y * 65536 + (size_t)(k0 + rr) * 256 + t0 + c] = tile[c][rr];
}

// ---- QKV projection (fp32 math, bf16 stores; V transposed) ----
__global__ __launch_bounds__(256) void k_qkv(const float* __restrict__ x,
                                             const float* __restrict__ bq,
                                             const float* __restrict__ bk,
                                             const float* __restrict__ bv,
                                             float* __restrict__ ws) {
    __shared__ float xs[16 * 768];
    const float* wqT = ws + OFF_WQT;
    const float* wkT = ws + OFF_WKT;
    const float* wvT = ws + OFF_WVT;
    __bf16* Q16 = (__bf16*)(ws + OFF_Q16);
    __bf16* K16 = Q16 + K16OFF;
    __bf16* V16 = Q16 + V16OFF;
    int t = threadIdx.x;
    int row0 = blockIdx.x * 16;
    for (int idx = t; idx < 16 * 768; idx += 256)
        xs[idx] = x[(size_t)row0 * 768 + idx];
    __syncthreads();

    float aq[16], ak[16], av[16];
#pragma unroll
    for (int r = 0; r < 16; r++) { aq[r] = 0.f; ak[r] = 0.f; av[r] = 0.f; }

    for (int kk = 0; kk < 256; kk += 4) {
        float wq0 = wqT[(kk + 0) * 256 + t], wq1 = wqT[(kk + 1) * 256 + t];
        float wq2 = wqT[(kk + 2) * 256 + t], wq3 = wqT[(kk + 3) * 256 + t];
        float wk0 = wkT[(kk + 0) * 256 + t], wk1 = wkT[(kk + 1) * 256 + t];
        float wk2 = wkT[(kk + 2) * 256 + t], wk3 = wkT[(kk + 3) * 256 + t];
        float wv0 = wvT[(kk + 0) * 256 + t], wv1 = wvT[(kk + 1) * 256 + t];
        float wv2 = wvT[(kk + 2) * 256 + t], wv3 = wvT[(kk + 3) * 256 + t];
#pragma unroll
        for (int r = 0; r < 16; r++) {
            float4 xq = *(const float4*)(xs + r * 768 + kk);
            float4 xk = *(const float4*)(xs + r * 768 + 256 + kk);
            float4 xv = *(const float4*)(xs + r * 768 + 512 + kk);
            aq[r] += xq.x * wq0 + xq.y * wq1 + xq.z * wq2 + xq.w * wq3;
            ak[r] += xk.x * wk0 + xk.y * wk1 + xk.z * wk2 + xk.w * wk3;
            av[r] += xv.x * wv0 + xv.y * wv1 + xv.z * wv2 + xv.w * wv3;
        }
    }
    float biasq = bq[t], biask = bk[t], biasv = bv[t];
    int h = t >> 6, d = t & 63;
#pragma unroll
    for (int r = 0; r < 16; r++) {
        int row = row0 + r;
        int b = row >> 12, s = row & 4095;
        int bh = b * HH + h;
        Q16[((size_t)bh * SEQ + s) * 64 + d] = (__bf16)(aq[r] + biasq);
        K16[((size_t)bh * SEQ + s) * 64 + d] = (__bf16)(ak[r] + biask);
        V16[((size_t)bh * 64 + d) * SEQ + s] = (__bf16)(av[r] + biasv);
    }
}

// ---- pass 1 (MFMA): Z_j = sum_i exp(s_ij - 16), fixed shift, no max ----
// grid (64 jblk, 4 isplit, 8 bh); wave owns 16 j, streams 1024 i.
__global__ __launch_bounds__(256) void k_colstats(float* __restrict__ ws) {
    int t = threadIdx.x, lane = t & 63, w = t >> 6;
    int jb = blockIdx.x, iy = blockIdx.y, bh = blockIdx.z;
    int j0 = jb * 64 + w * 16;
    int mrow = lane & 15, quad = lane >> 4;
    const __bf16* Q16 = (const __bf16*)(ws + OFF_Q16);
    const __bf16* K16 = Q16 + K16OFF;
    const __bf16* kb = K16 + ((size_t)bh * SEQ + j0 + mrow) * 64 + quad * 8;
    bf16x8 bk0 = *(const bf16x8*)(kb);
    bf16x8 bk1 = *(const bf16x8*)(kb + 32);
    const __bf16* qb = Q16 + ((size_t)bh * SEQ + iy * 1024 + mrow) * 64 + quad * 8;
    float z = 0.f;
    for (int ic = 0; ic < 64; ic++) {
        const __bf16* qp = qb + (size_t)ic * 16 * 64;
        bf16x8 aq0 = *(const bf16x8*)(qp);
        bf16x8 aq1 = *(const bf16x8*)(qp + 32);
        f32x4 c = {0.f, 0.f, 0.f, 0.f};
        c = mf(aq0, bk0, c);
        c = mf(aq1, bk1, c);
#pragma unroll
        for (int r = 0; r < 4; r++)
            z += __expf(fmaf(c[r], SCALE, -16.0f));
    }
    z += __shfl_xor(z, 16, 64);
    z += __shfl_xor(z, 32, 64);
    if (lane < 16)
        ws[OFF_PZ + (size_t)iy * 32768 + (size_t)bh * SEQ + j0 + lane] = z;
}

// ---- pass 1b: a_j = -16 - ln(sum of partials) ----
__global__ void k_afin(float* __restrict__ ws) {
    int idx = blockIdx.x * 256 + threadIdx.x;  // 0..32767
    const float* pz = ws + OFF_PZ;
    float Z = pz[idx] + pz[32768 + (size_t)idx] + pz[65536 + (size_t)idx] +
              pz[98304 + (size_t)idx];
    ws[OFF_A + idx] = -16.0f - __logf(Z);
}

// ---- pass 2 (MFMA): O[i][d] = sum_j exp(fma(c,SCALE,a_j)) * V[j][d] ----
// grid (64 iblk, 4 jsplit, 8 bh); wave owns 16 i, streams 1024 j in 32-chunks.
__global__ __launch_bounds__(256) void k_attnpv(float* __restrict__ ws) {
    __shared__ __bf16 ptile[4 * 640];    // per-wave 16x32 P tile, row stride 40
    int t = threadIdx.x, lane = t & 63, w = t >> 6;
    int jy = blockIdx.y, bh = blockIdx.z;
    int i0 = blockIdx.x * 64 + w * 16;
    int mrow = lane & 15, quad = lane >> 4;
    const __bf16* Q16 = (const __bf16*)(ws + OFF_Q16);
    const __bf16* K16 = Q16 + K16OFF;
    const __bf16* V16 = Q16 + V16OFF;
    const float* Ac = ws + OFF_A + (size_t)bh * SEQ;
    __bf16* pt = ptile + w * 640;

    const __bf16* qb = Q16 + ((size_t)bh * SEQ + i0 + mrow) * 64 + quad * 8;
    bf16x8 aq0 = *(const bf16x8*)(qb);
    bf16x8 aq1 = *(const bf16x8*)(qb + 32);

    f32x4 oacc[2][4];
#pragma unroll
    for (int pp = 0; pp < 2; pp++)
#pragma unroll
        for (int nd = 0; nd < 4; nd++) oacc[pp][nd] = {0.f, 0.f, 0.f, 0.f};

    int jbase = jy * 1024;
    for (int jt = 0; jt < 1024; jt += 32) {
        int j0 = jbase + jt;
        const __bf16* kb = K16 + ((size_t)bh * SEQ + j0 + mrow) * 64 + quad * 8;
#pragma unroll
        for (int nt = 0; nt < 2; nt++) {
            bf16x8 bk0 = *(const bf16x8*)(kb + (size_t)nt * 16 * 64);
            bf16x8 bk1 = *(const bf16x8*)(kb + (size_t)nt * 16 * 64 + 32);
            f32x4 c = {0.f, 0.f, 0.f, 0.f};
            c = mf(aq0, bk0, c);
            c = mf(aq1, bk1, c);
            float aj = Ac[j0 + nt * 16 + mrow];
#pragma unroll
            for (int r = 0; r < 4; r++) {
                float p = __expf(fmaf(c[r], SCALE, aj));
                pt[(quad * 4 + r) * 40 + nt * 16 + mrow] = (__bf16)p;
            }
        }
        // C-layout -> A-layout via per-wave LDS tile (same-wave, in-order DS)
        bf16x8 ap = *(const bf16x8*)(pt + mrow * 40 + quad * 8);
        const __bf16* vb = V16 + ((size_t)bh * 64 + mrow) * SEQ + j0 + quad * 8;
        int pp = (jt >> 5) & 1;
#pragma unroll
        for (int nd = 0; nd < 4; nd++) {
            bf16x8 bv = *(const bf16x8*)(vb + (size_t)nd * 16 * SEQ);
            oacc[pp][nd] = mf(ap, bv, oacc[pp][nd]);
        }
    }

    float* po = ws + OFF_PO + ((size_t)(jy * 8 + bh) * SEQ) * 64;
#pragma unroll
    for (int nd = 0; nd < 4; nd++) {
#pragma unroll
        for (int r = 0; r < 4; r++) {
            int i = i0 + quad * 4 + r;
            int d = nd * 16 + mrow;
            po[(size_t)i * 64 + d] = oacc[0][nd][r] + oacc[1][nd][r];
        }
    }
}

// ---- output projection: (merged partials) @ wo.T + bo, fp32 out ----
__global__ __launch_bounds__(256) void k_outproj(const float* __restrict__ bo,
                                                 const float* __restrict__ ws,
                                                 float* __restrict__ out) {
    __shared__ float xs[16 * 256];
    int t = threadIdx.x;
    int row0 = blockIdx.x * 16;
    const float* po = ws + OFF_PO;
    const float* woT = ws + OFF_WOT;
    for (int idx = t; idx < 16 * 256; idx += 256) {
        int r = idx >> 8, c = idx & 255;
        int h = c >> 6, d = c & 63;
        int row = row0 + r;
        int b = row >> 12, i = row & 4095;
        size_t base = ((size_t)(b * HH + h) * SEQ + i) * 64 + d;
        xs[idx] = po[base] + po[base + (size_t)8 * SEQ * 64]
                + po[base + (size_t)16 * SEQ * 64] + po[base + (size_t)24 * SEQ * 64];
    }
    __syncthreads();
    float acc[16];
#pragma unroll
    for (int r = 0; r < 16; r++) acc[r] = 0.f;
    for (int kk = 0; kk < 256; kk += 4) {
        float w0 = woT[(kk + 0) * 256 + t], w1 = woT[(kk + 1) * 256 + t];
        float w2 = woT[(kk + 2) * 256 + t], w3 = woT[(kk + 3) * 256 + t];
#pragma unroll
        for (int r = 0; r < 16; r++) {
            float4 xv = *(const float4*)(xs + r * 256 + kk);
            acc[r] += xv.x * w0 + xv.y * w1 + xv.z * w2 + xv.w * w3;
        }
    }
    float bias = bo[t];
#pragma unroll
    for (int r = 0; r < 16; r++)
        out[(size_t)(row0 + r) * 256 + t] = acc[r] + bias;
}

extern "C" void kernel_launch(void* const* d_in, const int* in_sizes, int n_in,
                              void* d_out, int out_size, void* d_ws, size_t ws_size,
                              hipStream_t stream) {
    const float* x  = (const float*)d_in[0];
    const float* wq = (const float*)d_in[1];
    const float* bq = (const float*)d_in[2];
    const float* wk = (const float*)d_in[3];
    const float* bk = (const float*)d_in[4];
    const float* wv = (const float*)d_in[5];
    const float* bv = (const float*)d_in[6];
    const float* wo = (const float*)d_in[7];
    const float* bo = (const float*)d_in[8];
    float* ws = (float*)d_ws;
    float* out = (float*)d_out;

    k_transpose<<<dim3(4, 4, 4), 256, 0, stream>>>(wq, wk, wv, wo, ws);
    k_qkv<<<512, 256, 0, stream>>>(x, bq, bk, bv, ws);
    k_colstats<<<dim3(64, 4, 8), 256, 0, stream>>>(ws);
    k_afin<<<128, 256, 0, stream>>>(ws);
    k_attnpv<<<dim3(64, 4, 8), 256, 0, stream>>>(ws);
    k_outproj<<<512, 256, 0, stream>>>(bo, ws, out);
}

// Round 10
// 508.768 us; speedup vs baseline: 1.1717x; 1.1717x over previous
//
#include <hip/hip_runtime.h>

#define SEQ   4096
#define HH    4
#define SCALE 0.125f

typedef __bf16 bf16x8 __attribute__((ext_vector_type(8)));
typedef __bf16 bf16x4 __attribute__((ext_vector_type(4)));
typedef float  f32x4  __attribute__((ext_vector_type(4)));

// ---- ws layout (float offsets), 62.6 MB total (< proven 70.5 MB) ----
// Facts: inputs fp32, output fp32 (R6), ws >= 70.5 MB (R2==R3).
// MFMA frag layouts HW-validated by R8 pass: A[m=l&15][k=q*8+e],
// B[n=l&15][k=q*8+e], C col=l&15 row=q*4+r.
constexpr size_t OFF_W16  = 0;         // 4x65536 bf16 (wq,wk,wv,wo row-major)
constexpr size_t OFF_A    = 131072;    // [bh*S+j] a_j = -16 - ln(Z_j)
constexpr size_t OFF_PZ   = 163840;    // [4][32768]
constexpr size_t OFF_PO   = 294912;    // [4jy][8bh][4096][64] fp32 partial O
constexpr size_t OFF_AO16 = 8683520;   // 8192x256 bf16 merged attn out
constexpr size_t OFF_X16  = 9732096;   // 6291456 bf16 (x cast)
constexpr size_t OFF_Q16  = 12877824;  // Q,K bf16 [bh][s][64]; V^T [bh][d][s]
constexpr size_t K16OFF   = 2097152;
constexpr size_t V16OFF   = 4194304;

__device__ __forceinline__ f32x4 mf(bf16x8 a, bf16x8 b, f32x4 c) {
    return __builtin_amdgcn_mfma_f32_16x16x32_bf16(a, b, c, 0, 0, 0);
}

// ---- cast x to bf16 ----
__global__ void k_castx(const float* __restrict__ x, float* __restrict__ ws) {
    size_t i4 = ((size_t)blockIdx.x * 256 + threadIdx.x) * 4;
    float4 v = *(const float4*)(x + i4);
    bf16x4 o = {(__bf16)v.x, (__bf16)v.y, (__bf16)v.z, (__bf16)v.w};
    *(bf16x4*)((__bf16*)(ws + OFF_X16) + i4) = o;
}

// ---- cast weights to bf16 (row-major kept) ----
__global__ void k_castw(const float* __restrict__ wq, const float* __restrict__ wk,
                        const float* __restrict__ wv, const float* __restrict__ wo,
                        float* __restrict__ ws) {
    int y = blockIdx.y;
    const float* src = (y == 0) ? wq : (y == 1) ? wk : (y == 2) ? wv : wo;
    size_t i4 = ((size_t)blockIdx.x * 256 + threadIdx.x) * 4;
    float4 v = *(const float4*)(src + i4);
    bf16x4 o = {(__bf16)v.x, (__bf16)v.y, (__bf16)v.z, (__bf16)v.w};
    *(bf16x4*)((__bf16*)(ws + OFF_W16) + (size_t)y * 65536 + i4) = o;
}

// ---- QKV projection via MFMA: grid (128 rowblk, 3 proj) ----
__global__ __launch_bounds__(256) void k_qkv_mfma(const float* __restrict__ bq,
                                                  const float* __restrict__ bk,
                                                  const float* __restrict__ bv,
                                                  float* __restrict__ ws) {
    int t = threadIdx.x, lane = t & 63, w = t >> 6;
    int yw = blockIdx.y;
    int row0 = blockIdx.x * 64 + w * 16;
    int mrow = lane & 15, quad = lane >> 4;
    const __bf16* X16 = (const __bf16*)(ws + OFF_X16);
    const __bf16* W16 = (const __bf16*)(ws + OFF_W16) + (size_t)yw * 65536;
    const float* bias = (yw == 0) ? bq : (yw == 1) ? bk : bv;
    __bf16* Qb = (__bf16*)(ws + OFF_Q16);
    f32x4 acc[16];
#pragma unroll
    for (int n = 0; n < 16; n++) acc[n] = {0.f, 0.f, 0.f, 0.f};
    const __bf16* ap = X16 + (size_t)(row0 + mrow) * 768 + yw * 256 + quad * 8;
    const __bf16* bp = W16 + (size_t)mrow * 256 + quad * 8;
    for (int kc = 0; kc < 256; kc += 32) {
        bf16x8 a = *(const bf16x8*)(ap + kc);
#pragma unroll
        for (int nt = 0; nt < 16; nt++) {
            bf16x8 b = *(const bf16x8*)(bp + (size_t)nt * 16 * 256 + kc);
            acc[nt] = mf(a, b, acc[nt]);
        }
    }
#pragma unroll
    for (int nt = 0; nt < 16; nt++) {
        int n = nt * 16 + mrow;
        float bb = bias[n];
        int h = n >> 6, d = n & 63;
#pragma unroll
        for (int r = 0; r < 4; r++) {
            int sg = row0 + quad * 4 + r;
            int b_ = sg >> 12, s = sg & 4095;
            int bh = b_ * HH + h;
            float val = acc[nt][r] + bb;
            if (yw == 0)
                Qb[((size_t)bh * SEQ + s) * 64 + d] = (__bf16)val;
            else if (yw == 1)
                Qb[K16OFF + ((size_t)bh * SEQ + s) * 64 + d] = (__bf16)val;
            else
                Qb[V16OFF + ((size_t)bh * 64 + d) * SEQ + s] = (__bf16)val;
        }
    }
}

// ---- pass 1 (MFMA): Z_j = sum_i exp(s_ij - 16); Q-frag prefetch ----
__global__ __launch_bounds__(256) void k_colstats(float* __restrict__ ws) {
    int t = threadIdx.x, lane = t & 63, w = t >> 6;
    int jb = blockIdx.x, iy = blockIdx.y, bh = blockIdx.z;
    int j0 = jb * 64 + w * 16;
    int mrow = lane & 15, quad = lane >> 4;
    const __bf16* Q16 = (const __bf16*)(ws + OFF_Q16);
    const __bf16* K16 = Q16 + K16OFF;
    const __bf16* kb = K16 + ((size_t)bh * SEQ + j0 + mrow) * 64 + quad * 8;
    bf16x8 bk0 = *(const bf16x8*)(kb);
    bf16x8 bk1 = *(const bf16x8*)(kb + 32);
    const __bf16* qb = Q16 + ((size_t)bh * SEQ + iy * 1024 + mrow) * 64 + quad * 8;
    bf16x8 a0 = *(const bf16x8*)(qb);
    bf16x8 a1 = *(const bf16x8*)(qb + 32);
    float z = 0.f;
    for (int ic = 0; ic < 64; ic++) {
        int icn = (ic + 1) & 63;
        const __bf16* qn = qb + (size_t)icn * 1024;
        bf16x8 n0 = *(const bf16x8*)(qn);
        bf16x8 n1 = *(const bf16x8*)(qn + 32);
        f32x4 c = {0.f, 0.f, 0.f, 0.f};
        c = mf(a0, bk0, c);
        c = mf(a1, bk1, c);
#pragma unroll
        for (int r = 0; r < 4; r++)
            z += __expf(fmaf(c[r], SCALE, -16.0f));
        a0 = n0; a1 = n1;
    }
    z += __shfl_xor(z, 16, 64);
    z += __shfl_xor(z, 32, 64);
    if (lane < 16)
        ws[OFF_PZ + (size_t)iy * 32768 + (size_t)bh * SEQ + j0 + lane] = z;
}

// ---- pass 1b: a_j = -16 - ln(sum of partials) ----
__global__ void k_afin(float* __restrict__ ws) {
    int idx = blockIdx.x * 256 + threadIdx.x;
    const float* pz = ws + OFF_PZ;
    float Z = pz[idx] + pz[32768 + (size_t)idx] + pz[65536 + (size_t)idx] +
              pz[98304 + (size_t)idx];
    ws[OFF_A + idx] = -16.0f - __logf(Z);
}

// ---- pass 2 (MFMA): software-pipelined K/A prefetch ----
// grid (64 iblk, 4 jsplit, 8 bh); wave owns 16 i, 32-j chunks.
__global__ __launch_bounds__(256) void k_attnpv(float* __restrict__ ws) {
    __shared__ __bf16 ptile[4 * 640];    // per-wave 16x32 tile, row stride 40
    int t = threadIdx.x, lane = t & 63, w = t >> 6;
    int jy = blockIdx.y, bh = blockIdx.z;
    int i0 = blockIdx.x * 64 + w * 16;
    int mrow = lane & 15, quad = lane >> 4;
    const __bf16* Q16 = (const __bf16*)(ws + OFF_Q16);
    const __bf16* K16 = Q16 + K16OFF;
    const __bf16* V16 = Q16 + V16OFF;
    const float* Ac = ws + OFF_A + (size_t)bh * SEQ;
    __bf16* pt = ptile + w * 640;

    const __bf16* qb = Q16 + ((size_t)bh * SEQ + i0 + mrow) * 64 + quad * 8;
    bf16x8 aq0 = *(const bf16x8*)(qb);
    bf16x8 aq1 = *(const bf16x8*)(qb + 32);

    f32x4 oacc[2][4];
#pragma unroll
    for (int pp = 0; pp < 2; pp++)
#pragma unroll
        for (int nd = 0; nd < 4; nd++) oacc[pp][nd] = {0.f, 0.f, 0.f, 0.f};

    int jbase = jy * 1024;
    const __bf16* kbase = K16 + ((size_t)bh * SEQ + mrow) * 64 + quad * 8;
    // prefetch chunk 0: K frags + a coefficients
    bf16x8 ck0 = *(const bf16x8*)(kbase + (size_t)jbase * 64);
    bf16x8 ck1 = *(const bf16x8*)(kbase + (size_t)jbase * 64 + 32);
    bf16x8 ck2 = *(const bf16x8*)(kbase + (size_t)(jbase + 16) * 64);
    bf16x8 ck3 = *(const bf16x8*)(kbase + (size_t)(jbase + 16) * 64 + 32);
    float ca0 = Ac[jbase + mrow], ca1 = Ac[jbase + 16 + mrow];

    for (int jt = 0; jt < 1024; jt += 32) {
        int j0 = jbase + jt;
        int jn = (jt + 32 < 1024) ? j0 + 32 : jbase;
        // issue next-chunk K/A loads first (consumed next iteration)
        bf16x8 nk0 = *(const bf16x8*)(kbase + (size_t)jn * 64);
        bf16x8 nk1 = *(const bf16x8*)(kbase + (size_t)jn * 64 + 32);
        bf16x8 nk2 = *(const bf16x8*)(kbase + (size_t)(jn + 16) * 64);
        bf16x8 nk3 = *(const bf16x8*)(kbase + (size_t)(jn + 16) * 64 + 32);
        float na0 = Ac[jn + mrow], na1 = Ac[jn + 16 + mrow];
        // issue V loads for current chunk early
        const __bf16* vb = V16 + ((size_t)bh * 64 + mrow) * SEQ + j0 + quad * 8;
        bf16x8 v0 = *(const bf16x8*)(vb);
        bf16x8 v1 = *(const bf16x8*)(vb + (size_t)16 * SEQ);
        bf16x8 v2 = *(const bf16x8*)(vb + (size_t)32 * SEQ);
        bf16x8 v3 = *(const bf16x8*)(vb + (size_t)48 * SEQ);
        // scores (K frags already resident from previous iteration)
        f32x4 c0 = {0.f, 0.f, 0.f, 0.f};
        c0 = mf(aq0, ck0, c0);
        c0 = mf(aq1, ck1, c0);
        f32x4 c1 = {0.f, 0.f, 0.f, 0.f};
        c1 = mf(aq0, ck2, c1);
        c1 = mf(aq1, ck3, c1);
#pragma unroll
        for (int r = 0; r < 4; r++) {
            float p0 = __expf(fmaf(c0[r], SCALE, ca0));
            pt[(quad * 4 + r) * 40 + mrow] = (__bf16)p0;
            float p1 = __expf(fmaf(c1[r], SCALE, ca1));
            pt[(quad * 4 + r) * 40 + 16 + mrow] = (__bf16)p1;
        }
        bf16x8 apf = *(const bf16x8*)(pt + mrow * 40 + quad * 8);
        int pp = (jt >> 5) & 1;
        oacc[pp][0] = mf(apf, v0, oacc[pp][0]);
        oacc[pp][1] = mf(apf, v1, oacc[pp][1]);
        oacc[pp][2] = mf(apf, v2, oacc[pp][2]);
        oacc[pp][3] = mf(apf, v3, oacc[pp][3]);
        ck0 = nk0; ck1 = nk1; ck2 = nk2; ck3 = nk3;
        ca0 = na0; ca1 = na1;
    }

    float* po = ws + OFF_PO + ((size_t)(jy * 8 + bh) * SEQ) * 64;
#pragma unroll
    for (int nd = 0; nd < 4; nd++) {
#pragma unroll
        for (int r = 0; r < 4; r++) {
            int i = i0 + quad * 4 + r;
            int d = nd * 16 + mrow;
            po[(size_t)i * 64 + d] = oacc[0][nd][r] + oacc[1][nd][r];
        }
    }
}

// ---- merge 4 j-split partials -> bf16 AO [row][256] ----
__global__ void k_merge(float* __restrict__ ws) {
    size_t i4 = ((size_t)blockIdx.x * 256 + threadIdx.x) * 4;
    int c = (int)(i4 & 255);
    int row = (int)(i4 >> 8);
    int h = c >> 6, d = c & 63;
    int b = row >> 12, i = row & 4095;
    const float* po = ws + OFF_PO;
    size_t base = ((size_t)(b * HH + h) * SEQ + i) * 64 + d;
    float4 s = *(const float4*)(po + base);
    const float4 s1 = *(const float4*)(po + base + (size_t)8 * SEQ * 64);
    const float4 s2 = *(const float4*)(po + base + (size_t)16 * SEQ * 64);
    const float4 s3 = *(const float4*)(po + base + (size_t)24 * SEQ * 64);
    s.x += s1.x + s2.x + s3.x; s.y += s1.y + s2.y + s3.y;
    s.z += s1.z + s2.z + s3.z; s.w += s1.w + s2.w + s3.w;
    bf16x4 o = {(__bf16)s.x, (__bf16)s.y, (__bf16)s.z, (__bf16)s.w};
    *(bf16x4*)((__bf16*)(ws + OFF_AO16) + i4) = o;
}

// ---- output projection via MFMA: AO16 @ wo16^T + bo, fp32 out ----
__global__ __launch_bounds__(256) void k_outproj_mfma(const float* __restrict__ bo,
                                                      float* __restrict__ ws,
                                                      float* __restrict__ out) {
    int t = threadIdx.x, lane = t & 63, w = t >> 6;
    int row0 = blockIdx.x * 64 + w * 16;
    int mrow = lane & 15, quad = lane >> 4;
    const __bf16* AO = (const __bf16*)(ws + OFF_AO16);
    const __bf16* W16 = (const __bf16*)(ws + OFF_W16) + (size_t)3 * 65536;
    f32x4 acc[16];
#pragma unroll
    for (int n = 0; n < 16; n++) acc[n] = {0.f, 0.f, 0.f, 0.f};
    const __bf16* ap = AO + (size_t)(row0 + mrow) * 256 + quad * 8;
    const __bf16* bp = W16 + (size_t)mrow * 256 + quad * 8;
    for (int kc = 0; kc < 256; kc += 32) {
        bf16x8 a = *(const bf16x8*)(ap + kc);
#pragma unroll
        for (int nt = 0; nt < 16; nt++) {
            bf16x8 b = *(const bf16x8*)(bp + (size_t)nt * 16 * 256 + kc);
            acc[nt] = mf(a, b, acc[nt]);
        }
    }
#pragma unroll
    for (int nt = 0; nt < 16; nt++) {
        int n = nt * 16 + mrow;
        float bb = bo[n];
#pragma unroll
        for (int r = 0; r < 4; r++) {
            int sg = row0 + quad * 4 + r;
            out[(size_t)sg * 256 + n] = acc[nt][r] + bb;
        }
    }
}

extern "C" void kernel_launch(void* const* d_in, const int* in_sizes, int n_in,
                              void* d_out, int out_size, void* d_ws, size_t ws_size,
                              hipStream_t stream) {
    const float* x  = (const float*)d_in[0];
    const float* wq = (const float*)d_in[1];
    const float* bq = (const float*)d_in[2];
    const float* wk = (const float*)d_in[3];
    const float* bk = (const float*)d_in[4];
    const float* wv = (const float*)d_in[5];
    const float* bv = (const float*)d_in[6];
    const float* wo = (const float*)d_in[7];
    const float* bo = (const float*)d_in[8];
    float* ws = (float*)d_ws;
    float* out = (float*)d_out;

    k_castx<<<6144, 256, 0, stream>>>(x, ws);
    k_castw<<<dim3(64, 4), 256, 0, stream>>>(wq, wk, wv, wo, ws);
    k_qkv_mfma<<<dim3(128, 3), 256, 0, stream>>>(bq, bk, bv, ws);
    k_colstats<<<dim3(64, 4, 8), 256, 0, stream>>>(ws);
    k_afin<<<128, 256, 0, stream>>>(ws);
    k_attnpv<<<dim3(64, 4, 8), 256, 0, stream>>>(ws);
    k_merge<<<2048, 256, 0, stream>>>(ws);
    k_outproj_mfma<<<128, 256, 0, stream>>>(bo, ws, out);
}

// Round 11
// 266.756 us; speedup vs baseline: 2.2346x; 1.9072x over previous
//
#include <hip/hip_runtime.h>

#define SEQ   4096
#define HH    4
#define SCALE 0.125f

typedef __bf16 bf16x8 __attribute__((ext_vector_type(8)));
typedef __bf16 bf16x4 __attribute__((ext_vector_type(4)));
typedef float  f32x4  __attribute__((ext_vector_type(4)));

// ---- ws layout (float offsets), 62.6 MB total (< proven 70.5 MB) ----
// Facts: inputs fp32, output fp32 (R6), ws >= 70.5 MB (R2==R3).
// Q,K stored FRAG-PACKED: [bh][tile16][frag2][lane64][e8] (1KB per frag-block,
// one contiguous wave-load). V stored packed for PV B-operand:
// [bh][jc32][nd4][lane64][e8].
constexpr size_t OFF_W16  = 0;         // 4x65536 bf16 weights row-major
constexpr size_t OFF_A    = 131072;    // [bh*S+j] a_j = -16 - ln(Z_j)
constexpr size_t OFF_PZ   = 163840;    // [4][32768]
constexpr size_t OFF_PO   = 294912;    // [4jy][8bh][4096][64] fp32 partial O
constexpr size_t OFF_AO16 = 8683520;   // 8192x256 bf16 merged attn out
constexpr size_t OFF_X16  = 9732096;   // 6291456 bf16 (x cast)
constexpr size_t OFF_Q16  = 12877824;  // packed Q,K,V bf16 regions
constexpr size_t K16OFF   = 2097152;
constexpr size_t V16OFF   = 4194304;

__device__ __forceinline__ f32x4 mf(bf16x8 a, bf16x8 b, f32x4 c) {
    return __builtin_amdgcn_mfma_f32_16x16x32_bf16(a, b, c, 0, 0, 0);
}

// async global->LDS, 16B/lane; LDS dst = base + lane*16 (wave-uniform base)
__device__ __forceinline__ void gload16(const __bf16* g, __bf16* l) {
    __builtin_amdgcn_global_load_lds(
        (const __attribute__((address_space(1))) unsigned int*)g,
        (__attribute__((address_space(3))) unsigned int*)l, 16, 0, 0);
}

// ---- cast x to bf16 ----
__global__ void k_castx(const float* __restrict__ x, float* __restrict__ ws) {
    size_t i4 = ((size_t)blockIdx.x * 256 + threadIdx.x) * 4;
    float4 v = *(const float4*)(x + i4);
    bf16x4 o = {(__bf16)v.x, (__bf16)v.y, (__bf16)v.z, (__bf16)v.w};
    *(bf16x4*)((__bf16*)(ws + OFF_X16) + i4) = o;
}

// ---- cast weights to bf16 (row-major kept) ----
__global__ void k_castw(const float* __restrict__ wq, const float* __restrict__ wk,
                        const float* __restrict__ wv, const float* __restrict__ wo,
                        float* __restrict__ ws) {
    int y = blockIdx.y;
    const float* src = (y == 0) ? wq : (y == 1) ? wk : (y == 2) ? wv : wo;
    size_t i4 = ((size_t)blockIdx.x * 256 + threadIdx.x) * 4;
    float4 v = *(const float4*)(src + i4);
    bf16x4 o = {(__bf16)v.x, (__bf16)v.y, (__bf16)v.z, (__bf16)v.w};
    *(bf16x4*)((__bf16*)(ws + OFF_W16) + (size_t)y * 65536 + i4) = o;
}

// ---- QKV projection via MFMA; epilogue writes FRAG-PACKED layouts ----
__global__ __launch_bounds__(256) void k_qkv_mfma(const float* __restrict__ bq,
                                                  const float* __restrict__ bk,
                                                  const float* __restrict__ bv,
                                                  float* __restrict__ ws) {
    int t = threadIdx.x, lane = t & 63, w = t >> 6;
    int yw = blockIdx.y;
    int row0 = blockIdx.x * 64 + w * 16;
    int mrow = lane & 15, quad = lane >> 4;
    const __bf16* X16 = (const __bf16*)(ws + OFF_X16);
    const __bf16* W16 = (const __bf16*)(ws + OFF_W16) + (size_t)yw * 65536;
    const float* bias = (yw == 0) ? bq : (yw == 1) ? bk : bv;
    __bf16* Qb = (__bf16*)(ws + OFF_Q16);
    f32x4 acc[16];
#pragma unroll
    for (int n = 0; n < 16; n++) acc[n] = {0.f, 0.f, 0.f, 0.f};
    const __bf16* ap = X16 + (size_t)(row0 + mrow) * 768 + yw * 256 + quad * 8;
    const __bf16* bp = W16 + (size_t)mrow * 256 + quad * 8;
    for (int kc = 0; kc < 256; kc += 32) {
        bf16x8 a = *(const bf16x8*)(ap + kc);
#pragma unroll
        for (int nt = 0; nt < 16; nt++) {
            bf16x8 b = *(const bf16x8*)(bp + (size_t)nt * 16 * 256 + kc);
            acc[nt] = mf(a, b, acc[nt]);
        }
    }
#pragma unroll
    for (int nt = 0; nt < 16; nt++) {
        int n = nt * 16 + mrow;
        float bb = bias[n];
        int h = n >> 6, d = n & 63;
#pragma unroll
        for (int r = 0; r < 4; r++) {
            int sg = row0 + quad * 4 + r;
            int b_ = sg >> 12, s = sg & 4095;
            int bh = b_ * HH + h;
            float val = acc[nt][r] + bb;
            if (yw <= 1) {
                int tile = s >> 4, m = s & 15, frag = d >> 5, q2 = (d >> 3) & 3, e = d & 7;
                size_t idx = (((size_t)bh * 256 + tile) * 2 + frag) * 512 +
                             (size_t)(q2 * 16 + m) * 8 + e;
                ((yw == 0) ? Qb : Qb + K16OFF)[idx] = (__bf16)val;
            } else {
                int jc = s >> 5, qk = (s >> 3) & 3, e = s & 7;
                int nd = d >> 4, nl = d & 15;
                size_t idx = (((size_t)bh * 128 + jc) * 4 + nd) * 512 +
                             (size_t)(qk * 16 + nl) * 8 + e;
                Qb[V16OFF + idx] = (__bf16)val;
            }
        }
    }
}

// ---- pass 1 (MFMA): Z_j = sum_i exp(s_ij - 16); packed contiguous loads ----
// grid (64 jb, 4 iy, 8 bh); wave owns 16 j (tile jb*4+w), streams 1024 i.
__global__ __launch_bounds__(256) void k_colstats(float* __restrict__ ws) {
    int t = threadIdx.x, lane = t & 63, w = t >> 6;
    int jb = blockIdx.x, iy = blockIdx.y, bh = blockIdx.z;
    int jt = jb * 4 + w;
    const __bf16* Qp = (const __bf16*)(ws + OFF_Q16);
    const __bf16* Kp = Qp + K16OFF;
    const __bf16* kb = Kp + (((size_t)bh * 256 + jt) * 2) * 512 + lane * 8;
    bf16x8 bk0 = *(const bf16x8*)(kb);
    bf16x8 bk1 = *(const bf16x8*)(kb + 512);
    const __bf16* qb = Qp + (((size_t)bh * 256 + iy * 64) * 2) * 512 + lane * 8;
    bf16x8 a0 = *(const bf16x8*)(qb);
    bf16x8 a1 = *(const bf16x8*)(qb + 512);
    float z = 0.f;
    for (int ic = 0; ic < 64; ic++) {
        const __bf16* qn = qb + (size_t)((ic + 1) & 63) * 1024;
        bf16x8 n0 = *(const bf16x8*)(qn);
        bf16x8 n1 = *(const bf16x8*)(qn + 512);
        f32x4 c = {0.f, 0.f, 0.f, 0.f};
        c = mf(a0, bk0, c);
        c = mf(a1, bk1, c);
#pragma unroll
        for (int r = 0; r < 4; r++)
            z += __expf(fmaf(c[r], SCALE, -16.0f));
        a0 = n0; a1 = n1;
    }
    z += __shfl_xor(z, 16, 64);
    z += __shfl_xor(z, 32, 64);
    if (lane < 16)
        ws[OFF_PZ + (size_t)iy * 32768 + (size_t)bh * SEQ + jt * 16 + lane] = z;
}

// ---- pass 1b: a_j = -16 - ln(sum of partials) ----
__global__ void k_afin(float* __restrict__ ws) {
    int idx = blockIdx.x * 256 + threadIdx.x;
    const float* pz = ws + OFF_PZ;
    float Z = pz[idx] + pz[32768 + (size_t)idx] + pz[65536 + (size_t)idx] +
              pz[98304 + (size_t)idx];
    ws[OFF_A + idx] = -16.0f - __logf(Z);
}

// ---- pass 2: K/V chunk staged to LDS once per block (4x traffic cut) ----
// grid (64 iblk, 4 jy, 8 bh); wave owns i-tile blockIdx.x*4+w (16 i).
__global__ __launch_bounds__(256) void k_attnpv(float* __restrict__ ws) {
    __shared__ __bf16 ldsK[2048], ldsV[2048], ptile[4 * 640];
    int t = threadIdx.x, lane = t & 63, w = t >> 6;
    int jy = blockIdx.y, bh = blockIdx.z;
    int it = blockIdx.x * 4 + w;
    int mrow = lane & 15, quad = lane >> 4;
    const __bf16* Qp = (const __bf16*)(ws + OFF_Q16);
    const __bf16* Kp = Qp + K16OFF;
    const __bf16* Vp = Qp + V16OFF;
    const float* Ac = ws + OFF_A + (size_t)bh * SEQ;
    __bf16* pt = ptile + w * 640;

    const __bf16* qb = Qp + (((size_t)bh * 256 + it) * 2) * 512 + lane * 8;
    bf16x8 aq0 = *(const bf16x8*)(qb);
    bf16x8 aq1 = *(const bf16x8*)(qb + 512);

    f32x4 oacc[2][4];
#pragma unroll
    for (int pp = 0; pp < 2; pp++)
#pragma unroll
        for (int nd = 0; nd < 4; nd++) oacc[pp][nd] = {0.f, 0.f, 0.f, 0.f};

    int jbase = jy * 1024;
    for (int jt = 0; jt < 1024; jt += 32) {
        int j0 = jbase + jt;
        __syncthreads();   // prev chunk's LDS reads done before overwrite
        // stage K chunk (4KB) + V chunk (4KB): wave w moves unit w of each
        const __bf16* kg = Kp + ((size_t)bh * 256 + (j0 >> 4)) * 1024 +
                           (size_t)w * 512 + (size_t)lane * 8;
        gload16(kg, ldsK + w * 512);
        const __bf16* vg = Vp + ((size_t)bh * 128 + (j0 >> 5)) * 2048 +
                           (size_t)w * 512 + (size_t)lane * 8;
        gload16(vg, ldsV + w * 512);
        float ca0 = Ac[j0 + mrow], ca1 = Ac[j0 + 16 + mrow];
        __syncthreads();   // staging complete (compiler drains vmcnt)

        bf16x8 ck0 = *(const bf16x8*)(ldsK + lane * 8);
        bf16x8 ck1 = *(const bf16x8*)(ldsK + 512 + lane * 8);
        bf16x8 ck2 = *(const bf16x8*)(ldsK + 1024 + lane * 8);
        bf16x8 ck3 = *(const bf16x8*)(ldsK + 1536 + lane * 8);
        f32x4 c0 = {0.f, 0.f, 0.f, 0.f};
        c0 = mf(aq0, ck0, c0);
        c0 = mf(aq1, ck1, c0);
        f32x4 c1 = {0.f, 0.f, 0.f, 0.f};
        c1 = mf(aq0, ck2, c1);
        c1 = mf(aq1, ck3, c1);
#pragma unroll
        for (int r = 0; r < 4; r++) {
            float p0 = __expf(fmaf(c0[r], SCALE, ca0));
            pt[(quad * 4 + r) * 40 + mrow] = (__bf16)p0;
            float p1 = __expf(fmaf(c1[r], SCALE, ca1));
            pt[(quad * 4 + r) * 40 + 16 + mrow] = (__bf16)p1;
        }
        bf16x8 apf = *(const bf16x8*)(pt + mrow * 40 + quad * 8);
        int pp = (jt >> 5) & 1;
#pragma unroll
        for (int nd = 0; nd < 4; nd++) {
            bf16x8 bv = *(const bf16x8*)(ldsV + nd * 512 + lane * 8);
            oacc[pp][nd] = mf(apf, bv, oacc[pp][nd]);
        }
    }

    float* po = ws + OFF_PO + ((size_t)(jy * 8 + bh) * SEQ) * 64;
#pragma unroll
    for (int nd = 0; nd < 4; nd++) {
#pragma unroll
        for (int r = 0; r < 4; r++) {
            int i = it * 16 + quad * 4 + r;
            int d = nd * 16 + mrow;
            po[(size_t)i * 64 + d] = oacc[0][nd][r] + oacc[1][nd][r];
        }
    }
}

// ---- merge 4 j-split partials -> bf16 AO [row][256] ----
__global__ void k_merge(float* __restrict__ ws) {
    size_t i4 = ((size_t)blockIdx.x * 256 + threadIdx.x) * 4;
    int c = (int)(i4 & 255);
    int row = (int)(i4 >> 8);
    int h = c >> 6, d = c & 63;
    int b = row >> 12, i = row & 4095;
    const float* po = ws + OFF_PO;
    size_t base = ((size_t)(b * HH + h) * SEQ + i) * 64 + d;
    float4 s = *(const float4*)(po + base);
    const float4 s1 = *(const float4*)(po + base + (size_t)8 * SEQ * 64);
    const float4 s2 = *(const float4*)(po + base + (size_t)16 * SEQ * 64);
    const float4 s3 = *(const float4*)(po + base + (size_t)24 * SEQ * 64);
    s.x += s1.x + s2.x + s3.x; s.y += s1.y + s2.y + s3.y;
    s.z += s1.z + s2.z + s3.z; s.w += s1.w + s2.w + s3.w;
    bf16x4 o = {(__bf16)s.x, (__bf16)s.y, (__bf16)s.z, (__bf16)s.w};
    *(bf16x4*)((__bf16*)(ws + OFF_AO16) + i4) = o;
}

// ---- output projection via MFMA: AO16 @ wo16^T + bo, fp32 out ----
__global__ __launch_bounds__(256) void k_outproj_mfma(const float* __restrict__ bo,
                                                      float* __restrict__ ws,
                                                      float* __restrict__ out) {
    int t = threadIdx.x, lane = t & 63, w = t >> 6;
    int row0 = blockIdx.x * 64 + w * 16;
    int mrow = lane & 15, quad = lane >> 4;
    const __bf16* AO = (const __bf16*)(ws + OFF_AO16);
    const __bf16* W16 = (const __bf16*)(ws + OFF_W16) + (size_t)3 * 65536;
    f32x4 acc[16];
#pragma unroll
    for (int n = 0; n < 16; n++) acc[n] = {0.f, 0.f, 0.f, 0.f};
    const __bf16* ap = AO + (size_t)(row0 + mrow) * 256 + quad * 8;
    const __bf16* bp = W16 + (size_t)mrow * 256 + quad * 8;
    for (int kc = 0; kc < 256; kc += 32) {
        bf16x8 a = *(const bf16x8*)(ap + kc);
#pragma unroll
        for (int nt = 0; nt < 16; nt++) {
            bf16x8 b = *(const bf16x8*)(bp + (size_t)nt * 16 * 256 + kc);
            acc[nt] = mf(a, b, acc[nt]);
        }
    }
#pragma unroll
    for (int nt = 0; nt < 16; nt++) {
        int n = nt * 16 + mrow;
        float bb = bo[n];
#pragma unroll
        for (int r = 0; r < 4; r++) {
            int sg = row0 + quad * 4 + r;
            out[(size_t)sg * 256 + n] = acc[nt][r] + bb;
        }
    }
}

extern "C" void kernel_launch(void* const* d_in, const int* in_sizes, int n_in,
                              void* d_out, int out_size, void* d_ws, size_t ws_size,
                              hipStream_t stream) {
    const float* x  = (const float*)d_in[0];
    const float* wq = (const float*)d_in[1];
    const float* bq = (const float*)d_in[2];
    const float* wk = (const float*)d_in[3];
    const float* bk = (const float*)d_in[4];
    const float* wv = (const float*)d_in[5];
    const float* bv = (const float*)d_in[6];
    const float* wo = (const float*)d_in[7];
    const float* bo = (const float*)d_in[8];
    float* ws = (float*)d_ws;
    float* out = (float*)d_out;

    k_castx<<<6144, 256, 0, stream>>>(x, ws);
    k_castw<<<dim3(64, 4), 256, 0, stream>>>(wq, wk, wv, wo, ws);
    k_qkv_mfma<<<dim3(128, 3), 256, 0, stream>>>(bq, bk, bv, ws);
    k_colstats<<<dim3(64, 4, 8), 256, 0, stream>>>(ws);
    k_afin<<<128, 256, 0, stream>>>(ws);
    k_attnpv<<<dim3(64, 4, 8), 256, 0, stream>>>(ws);
    k_merge<<<2048, 256, 0, stream>>>(ws);
    k_outproj_mfma<<<128, 256, 0, stream>>>(bo, ws, out);
}

// Round 12
// 247.077 us; speedup vs baseline: 2.4126x; 1.0796x over previous
//
#include <hip/hip_runtime.h>

#define SEQ   4096
#define HH    4
#define SCALE 0.125f

typedef __bf16 bf16x8 __attribute__((ext_vector_type(8)));
typedef __bf16 bf16x4 __attribute__((ext_vector_type(4)));
typedef float  f32x4  __attribute__((ext_vector_type(4)));

// ---- ws layout (float offsets) ----
// Facts: inputs fp32, output fp32 (R6), ws >= 70.5 MB (R2==R3).
// Q,K frag-packed: [bh][tile16][frag2][lane64][e8]; V: [bh][jc32][nd4][512].
constexpr size_t OFF_W16  = 0;         // 4x65536 bf16 weights row-major
constexpr size_t OFF_A    = 131072;    // [bh*S+j] a_j = -16 - ln(Z_j)
constexpr size_t OFF_PZ   = 163840;    // [4][32768]
constexpr size_t OFF_AO   = 294912;    // [8192][256] fp32 attn out (atomic)
constexpr size_t OFF_X16  = 9732096;   // 6291456 bf16 (x cast)
constexpr size_t OFF_Q16  = 12877824;  // packed Q,K,V bf16 regions
constexpr size_t K16OFF   = 2097152;
constexpr size_t V16OFF   = 4194304;

__device__ __forceinline__ f32x4 mf(bf16x8 a, bf16x8 b, f32x4 c) {
    return __builtin_amdgcn_mfma_f32_16x16x32_bf16(a, b, c, 0, 0, 0);
}

// async global->LDS, 16B/lane; global ptr per-lane, LDS base wave-uniform
__device__ __forceinline__ void gload16(const __bf16* g, __bf16* l) {
    __builtin_amdgcn_global_load_lds(
        (const __attribute__((address_space(1))) unsigned int*)g,
        (__attribute__((address_space(3))) unsigned int*)l, 16, 0, 0);
}

// ---- prep: cast x, cast weights, zero AO — one kernel ----
__global__ void k_prep(const float* __restrict__ x,
                       const float* __restrict__ wq, const float* __restrict__ wk,
                       const float* __restrict__ wv, const float* __restrict__ wo,
                       float* __restrict__ ws) {
    int bx = blockIdx.x, t = threadIdx.x;
    if (bx < 6144) {
        size_t i4 = ((size_t)bx * 256 + t) * 4;
        float4 v = *(const float4*)(x + i4);
        bf16x4 o = {(__bf16)v.x, (__bf16)v.y, (__bf16)v.z, (__bf16)v.w};
        *(bf16x4*)((__bf16*)(ws + OFF_X16) + i4) = o;
    } else if (bx < 6400) {
        int q = bx - 6144;
        int y = q >> 6;
        const float* src = (y == 0) ? wq : (y == 1) ? wk : (y == 2) ? wv : wo;
        size_t i4 = ((size_t)(q & 63) * 256 + t) * 4;
        float4 v = *(const float4*)(src + i4);
        bf16x4 o = {(__bf16)v.x, (__bf16)v.y, (__bf16)v.z, (__bf16)v.w};
        *(bf16x4*)((__bf16*)(ws + OFF_W16) + (size_t)y * 65536 + i4) = o;
    } else {
        size_t i4 = ((size_t)(bx - 6400) * 256 + t) * 4;
        *(float4*)(ws + OFF_AO + i4) = make_float4(0.f, 0.f, 0.f, 0.f);
    }
}

// ---- QKV projection via MFMA; epilogue writes frag-packed layouts ----
__global__ __launch_bounds__(256) void k_qkv_mfma(const float* __restrict__ bq,
                                                  const float* __restrict__ bk,
                                                  const float* __restrict__ bv,
                                                  float* __restrict__ ws) {
    int t = threadIdx.x, lane = t & 63, w = t >> 6;
    int yw = blockIdx.y;
    int row0 = blockIdx.x * 64 + w * 16;
    int mrow = lane & 15, quad = lane >> 4;
    const __bf16* X16 = (const __bf16*)(ws + OFF_X16);
    const __bf16* W16 = (const __bf16*)(ws + OFF_W16) + (size_t)yw * 65536;
    const float* bias = (yw == 0) ? bq : (yw == 1) ? bk : bv;
    __bf16* Qb = (__bf16*)(ws + OFF_Q16);
    f32x4 acc[16];
#pragma unroll
    for (int n = 0; n < 16; n++) acc[n] = {0.f, 0.f, 0.f, 0.f};
    const __bf16* ap = X16 + (size_t)(row0 + mrow) * 768 + yw * 256 + quad * 8;
    const __bf16* bp = W16 + (size_t)mrow * 256 + quad * 8;
    for (int kc = 0; kc < 256; kc += 32) {
        bf16x8 a = *(const bf16x8*)(ap + kc);
#pragma unroll
        for (int nt = 0; nt < 16; nt++) {
            bf16x8 b = *(const bf16x8*)(bp + (size_t)nt * 16 * 256 + kc);
            acc[nt] = mf(a, b, acc[nt]);
        }
    }
#pragma unroll
    for (int nt = 0; nt < 16; nt++) {
        int n = nt * 16 + mrow;
        float bb = bias[n];
        int h = n >> 6, d = n & 63;
#pragma unroll
        for (int r = 0; r < 4; r++) {
            int sg = row0 + quad * 4 + r;
            int b_ = sg >> 12, s = sg & 4095;
            int bh = b_ * HH + h;
            float val = acc[nt][r] + bb;
            if (yw <= 1) {
                int tile = s >> 4, m = s & 15, frag = d >> 5, q2 = (d >> 3) & 3, e = d & 7;
                size_t idx = (((size_t)bh * 256 + tile) * 2 + frag) * 512 +
                             (size_t)(q2 * 16 + m) * 8 + e;
                ((yw == 0) ? Qb : Qb + K16OFF)[idx] = (__bf16)val;
            } else {
                int jc = s >> 5, qk = (s >> 3) & 3, e = s & 7;
                int nd = d >> 4, nl = d & 15;
                size_t idx = (((size_t)bh * 128 + jc) * 4 + nd) * 512 +
                             (size_t)(qk * 16 + nl) * 8 + e;
                Qb[V16OFF + idx] = (__bf16)val;
            }
        }
    }
}

// ---- pass 1: Z_j = sum_i exp(s_ij - 16); 32 j/wave, Q staged in LDS ----
// grid (32 jb, 4 iy, 8 bh); block = 128 j; Q chunks of 64 i double-buffered.
__global__ __launch_bounds__(256) void k_colstats(float* __restrict__ ws) {
    __shared__ __bf16 qbuf[2][4096];
    int t = threadIdx.x, lane = t & 63, w = t >> 6;
    int jb = blockIdx.x, iy = blockIdx.y, bh = blockIdx.z;
    int jt0 = jb * 8 + w * 2;
    const __bf16* Qp = (const __bf16*)(ws + OFF_Q16);
    const __bf16* Kp = Qp + K16OFF;
    const __bf16* kb = Kp + (((size_t)bh * 256 + jt0) * 2) * 512 + lane * 8;
    bf16x8 bk00 = *(const bf16x8*)(kb);
    bf16x8 bk01 = *(const bf16x8*)(kb + 512);
    bf16x8 bk10 = *(const bf16x8*)(kb + 1024);
    bf16x8 bk11 = *(const bf16x8*)(kb + 1536);
    // stage chunk 0
    const __bf16* q0 = Qp + (((size_t)bh * 256 + iy * 64) * 2) * 512 +
                       w * 1024 + lane * 8;
    gload16(q0, qbuf[0] + w * 1024);
    gload16(q0 + 512, qbuf[0] + w * 1024 + 512);
    __syncthreads();
    float z0 = 0.f, z1 = 0.f;
    for (int ic = 0; ic < 16; ic++) {
        const __bf16* cur = qbuf[ic & 1];
        if (ic < 15) {
            const __bf16* qn = Qp + (((size_t)bh * 256 + iy * 64 + (ic + 1) * 4) * 2) * 512 +
                               w * 1024 + lane * 8;
            gload16(qn, qbuf[(ic + 1) & 1] + w * 1024);
            gload16(qn + 512, qbuf[(ic + 1) & 1] + w * 1024 + 512);
        }
#pragma unroll
        for (int it = 0; it < 4; it++) {
            bf16x8 a0 = *(const bf16x8*)(cur + it * 1024 + lane * 8);
            bf16x8 a1 = *(const bf16x8*)(cur + it * 1024 + 512 + lane * 8);
            f32x4 c0 = {0.f, 0.f, 0.f, 0.f};
            c0 = mf(a0, bk00, c0);
            c0 = mf(a1, bk01, c0);
            f32x4 c1 = {0.f, 0.f, 0.f, 0.f};
            c1 = mf(a0, bk10, c1);
            c1 = mf(a1, bk11, c1);
#pragma unroll
            for (int r = 0; r < 4; r++) {
                z0 += __expf(fmaf(c0[r], SCALE, -16.0f));
                z1 += __expf(fmaf(c1[r], SCALE, -16.0f));
            }
        }
        __syncthreads();
    }
    z0 += __shfl_xor(z0, 16, 64);
    z0 += __shfl_xor(z0, 32, 64);
    z1 += __shfl_xor(z1, 16, 64);
    z1 += __shfl_xor(z1, 32, 64);
    if (lane < 16) {
        size_t o = OFF_PZ + (size_t)iy * 32768 + (size_t)bh * SEQ + jt0 * 16 + lane;
        ws[o] = z0;
        ws[o + 16] = z1;
    }
}

// ---- pass 1b: a_j = -16 - ln(sum of partials) ----
__global__ void k_afin(float* __restrict__ ws) {
    int idx = blockIdx.x * 256 + threadIdx.x;
    const float* pz = ws + OFF_PZ;
    float Z = pz[idx] + pz[32768 + (size_t)idx] + pz[65536 + (size_t)idx] +
              pz[98304 + (size_t)idx];
    ws[OFF_A + idx] = -16.0f - __logf(Z);
}

// ---- pass 2: 32 i/wave, K/V double-buffered in LDS, atomic fp32 epilogue ----
// grid (32 ib, 4 jy, 8 bh); block = 128 i; chunks of 32 j.
__global__ __launch_bounds__(256) void k_attnpv(float* __restrict__ ws) {
    __shared__ __bf16 ldsK[2][2048], ldsV[2][2048], ptile[4 * 1280];
    int t = threadIdx.x, lane = t & 63, w = t >> 6;
    int jy = blockIdx.y, bh = blockIdx.z;
    int it0 = blockIdx.x * 8 + w * 2;
    int mrow = lane & 15, quad = lane >> 4;
    const __bf16* Qp = (const __bf16*)(ws + OFF_Q16);
    const __bf16* Kp = Qp + K16OFF;
    const __bf16* Vp = Qp + V16OFF;
    const float* Ac = ws + OFF_A + (size_t)bh * SEQ;
    __bf16* pt = ptile + w * 1280;

    const __bf16* qb = Qp + (((size_t)bh * 256 + it0) * 2) * 512 + lane * 8;
    bf16x8 aq00 = *(const bf16x8*)(qb);
    bf16x8 aq01 = *(const bf16x8*)(qb + 512);
    bf16x8 aq10 = *(const bf16x8*)(qb + 1024);
    bf16x8 aq11 = *(const bf16x8*)(qb + 1536);

    f32x4 oacc[2][4];
#pragma unroll
    for (int tt = 0; tt < 2; tt++)
#pragma unroll
        for (int nd = 0; nd < 4; nd++) oacc[tt][nd] = {0.f, 0.f, 0.f, 0.f};

    int jbase = jy * 1024;
    // stage chunk 0
    {
        const __bf16* kg = Kp + (((size_t)bh * 256 + (jbase >> 4)) * 2) * 512 +
                           w * 512 + lane * 8;
        gload16(kg, ldsK[0] + w * 512);
        const __bf16* vg = Vp + (((size_t)bh * 128 + (jbase >> 5)) * 4) * 512 +
                           w * 512 + lane * 8;
        gload16(vg, ldsV[0] + w * 512);
    }
    __syncthreads();

    for (int jt = 0; jt < 32; jt++) {
        int j0 = jbase + jt * 32;
        const __bf16* curK = ldsK[jt & 1];
        const __bf16* curV = ldsV[jt & 1];
        if (jt < 31) {
            int jn = j0 + 32;
            const __bf16* kg = Kp + (((size_t)bh * 256 + (jn >> 4)) * 2) * 512 +
                               w * 512 + lane * 8;
            gload16(kg, ldsK[(jt + 1) & 1] + w * 512);
            const __bf16* vg = Vp + (((size_t)bh * 128 + (jn >> 5)) * 4) * 512 +
                               w * 512 + lane * 8;
            gload16(vg, ldsV[(jt + 1) & 1] + w * 512);
        }
        float ca0 = Ac[j0 + mrow], ca1 = Ac[j0 + 16 + mrow];
        bf16x8 ck0 = *(const bf16x8*)(curK + lane * 8);
        bf16x8 ck1 = *(const bf16x8*)(curK + 512 + lane * 8);
        bf16x8 ck2 = *(const bf16x8*)(curK + 1024 + lane * 8);
        bf16x8 ck3 = *(const bf16x8*)(curK + 1536 + lane * 8);
#pragma unroll
        for (int tt = 0; tt < 2; tt++) {
            bf16x8 a0 = tt ? aq10 : aq00;
            bf16x8 a1 = tt ? aq11 : aq01;
            f32x4 c0 = {0.f, 0.f, 0.f, 0.f};
            c0 = mf(a0, ck0, c0);
            c0 = mf(a1, ck1, c0);
            f32x4 c1 = {0.f, 0.f, 0.f, 0.f};
            c1 = mf(a0, ck2, c1);
            c1 = mf(a1, ck3, c1);
#pragma unroll
            for (int r = 0; r < 4; r++) {
                float p0 = __expf(fmaf(c0[r], SCALE, ca0));
                pt[(tt * 16 + quad * 4 + r) * 40 + mrow] = (__bf16)p0;
                float p1 = __expf(fmaf(c1[r], SCALE, ca1));
                pt[(tt * 16 + quad * 4 + r) * 40 + 16 + mrow] = (__bf16)p1;
            }
        }
        bf16x8 ap0 = *(const bf16x8*)(pt + mrow * 40 + quad * 8);
        bf16x8 ap1 = *(const bf16x8*)(pt + (16 + mrow) * 40 + quad * 8);
#pragma unroll
        for (int nd = 0; nd < 4; nd++) {
            bf16x8 bv = *(const bf16x8*)(curV + nd * 512 + lane * 8);
            oacc[0][nd] = mf(ap0, bv, oacc[0][nd]);
            oacc[1][nd] = mf(ap1, bv, oacc[1][nd]);
        }
        __syncthreads();
    }

    int b = bh >> 2, h = bh & 3;
    float* AO = ws + OFF_AO;
#pragma unroll
    for (int tt = 0; tt < 2; tt++) {
#pragma unroll
        for (int nd = 0; nd < 4; nd++) {
#pragma unroll
            for (int r = 0; r < 4; r++) {
                int i = (it0 + tt) * 16 + quad * 4 + r;
                int d = nd * 16 + mrow;
                atomicAdd(&AO[((size_t)(b * SEQ + i)) * 256 + h * 64 + d],
                          oacc[tt][nd][r]);
            }
        }
    }
}

// ---- output projection: fp32 AO -> bf16 frags inline, MFMA, fp32 out ----
__global__ __launch_bounds__(256) void k_outproj_mfma(const float* __restrict__ bo,
                                                      float* __restrict__ ws,
                                                      float* __restrict__ out) {
    int t = threadIdx.x, lane = t & 63, w = t >> 6;
    int row0 = blockIdx.x * 64 + w * 16;
    int mrow = lane & 15, quad = lane >> 4;
    const float* AO = ws + OFF_AO;
    const __bf16* W16 = (const __bf16*)(ws + OFF_W16) + (size_t)3 * 65536;
    f32x4 acc[16];
#pragma unroll
    for (int n = 0; n < 16; n++) acc[n] = {0.f, 0.f, 0.f, 0.f};
    const float* ap = AO + (size_t)(row0 + mrow) * 256 + quad * 8;
    const __bf16* bp = W16 + (size_t)mrow * 256 + quad * 8;
    for (int kc = 0; kc < 256; kc += 32) {
        float4 u = *(const float4*)(ap + kc);
        float4 v = *(const float4*)(ap + kc + 4);
        bf16x8 a = {(__bf16)u.x, (__bf16)u.y, (__bf16)u.z, (__bf16)u.w,
                    (__bf16)v.x, (__bf16)v.y, (__bf16)v.z, (__bf16)v.w};
#pragma unroll
        for (int nt = 0; nt < 16; nt++) {
            bf16x8 b = *(const bf16x8*)(bp + (size_t)nt * 16 * 256 + kc);
            acc[nt] = mf(a, b, acc[nt]);
        }
    }
#pragma unroll
    for (int nt = 0; nt < 16; nt++) {
        int n = nt * 16 + mrow;
        float bb = bo[n];
#pragma unroll
        for (int r = 0; r < 4; r++) {
            int sg = row0 + quad * 4 + r;
            out[(size_t)sg * 256 + n] = acc[nt][r] + bb;
        }
    }
}

extern "C" void kernel_launch(void* const* d_in, const int* in_sizes, int n_in,
                              void* d_out, int out_size, void* d_ws, size_t ws_size,
                              hipStream_t stream) {
    const float* x  = (const float*)d_in[0];
    const float* wq = (const float*)d_in[1];
    const float* bq = (const float*)d_in[2];
    const float* wk = (const float*)d_in[3];
    const float* bk = (const float*)d_in[4];
    const float* wv = (const float*)d_in[5];
    const float* bv = (const float*)d_in[6];
    const float* wo = (const float*)d_in[7];
    const float* bo = (const float*)d_in[8];
    float* ws = (float*)d_ws;
    float* out = (float*)d_out;

    k_prep<<<8448, 256, 0, stream>>>(x, wq, wk, wv, wo, ws);
    k_qkv_mfma<<<dim3(128, 3), 256, 0, stream>>>(bq, bk, bv, ws);
    k_colstats<<<dim3(32, 4, 8), 256, 0, stream>>>(ws);
    k_afin<<<128, 256, 0, stream>>>(ws);
    k_attnpv<<<dim3(32, 4, 8), 256, 0, stream>>>(ws);
    k_outproj_mfma<<<128, 256, 0, stream>>>(bo, ws, out);
}